// Round 3
// baseline (151.479 us; speedup 1.0000x reference)
//
#include <hip/hip_runtime.h>
#include <math.h>

// Shapes: B=4, N=8192, F=64; MLP: 67 -> 64 -> 32 -> 1
// d_out: [0,32768) boundary_prob | [32768,+2097152) features | last 4: conf
#define NB 4
#define NPTS 8192
#define OUT_FEAT_OFF 32768
#define OUT_CONF_OFF (32768 + 2097152)

// ---------------------------------------------------------------------------
// block reduce over 256 threads
// ---------------------------------------------------------------------------
__device__ __forceinline__ float blockReduceSum256(float v) {
    __shared__ float sred[4];
#pragma unroll
    for (int o = 32; o > 0; o >>= 1) v += __shfl_down(v, o, 64);
    const int w = threadIdx.x >> 6, l = threadIdx.x & 63;
    __syncthreads();
    if (l == 0) sred[w] = v;
    __syncthreads();
    return sred[0] + sred[1] + sred[2] + sred[3];
}

// ---------------------------------------------------------------------------
// Fused kernel: 512 blocks x 256 threads (2 blocks/CU, 2 waves/SIMD).
// Block = 64 points; wave w owns points [16w,16w+16).
// EXPLICIT operand placement (rounds 1-2 failed on compiler heuristics):
//   - weights in VGPRs, lane = output neuron: wv1[67] (lane j = W1[j][:]),
//     wv2[32] (lane = (j2 = ln&31, khalf = ln>>5)). Per-lane global loads ->
//     allocator cannot rematerialize them, they stay register-resident.
//   - activations via LDS hardware broadcast: x-reads are wave-uniform
//     addresses (same-address broadcast = conflict-free); h1 parked in LDS
//     with stride-1 b32 writes (2-way, free) and broadcast reads for L2.
// L3 reduced with shfl_xor tree; scores collected on lanes 0..15 for one
// coalesced store. Last-arriving block per batch computes the stats
// (round-2 tail: shfl scan, dd in LDS aliasing the dead MLP buffers).
// ---------------------------------------------------------------------------
__global__ __launch_bounds__(256, 2) void fused_kernel(
    const float* __restrict__ pts,    // (B,N,3)
    const float* __restrict__ feats,  // (B,N,64)
    const int* __restrict__ mask,     // (B,N)
    const float* __restrict__ W1,     // (64,67)
    const float* __restrict__ b1,
    const float* __restrict__ W2,     // (32,64)
    const float* __restrict__ b2,
    const float* __restrict__ W3,     // (1,32)
    const float* __restrict__ b3,
    float* __restrict__ out,
    int* __restrict__ counters,       // 4 ints in ws, pre-zeroed
    float* __restrict__ wsf)          // stats scratch (after counters)
{
    // smem pool, aliased across phases:
    //   MLP : sX  = [0,4352)   64 rows x pitch 68 (feats cols 0..63, xyz 64..66)
    //         sH1 = [4352,8704) 64 rows x pitch 68 (h1 cols 0..63)
    //   stats: ddl = smem[0..8191)  (sX/sH1 dead by then)
    __shared__ float smem[8704];
    float* const sX = smem;
    float* const sH1 = smem + 4352;
    __shared__ int sflag;
    __shared__ int swt[4];

    const int t = threadIdx.x;
    const int ln = t & 63;
    const int w = __builtin_amdgcn_readfirstlane(t >> 6);  // wave id (SGPR)
    const int prow = w * 16;                                // this wave's rows

    // ---- per-lane weight loads (issued early; latency overlaps staging)
    float wv1[67];
#pragma unroll
    for (int k = 0; k < 67; ++k) wv1[k] = W1[ln * 67 + k];
    const float b1v = b1[ln];
    const int j2 = ln & 31, kh = ln >> 5;
    float wv2[32];
    {
        const float* w2r = W2 + j2 * 64 + (kh << 5);  // 16B aligned
#pragma unroll
        for (int m = 0; m < 8; ++m) {
            const float4 v = *(const float4*)&w2r[4 * m];
            wv2[4*m+0] = v.x; wv2[4*m+1] = v.y;
            wv2[4*m+2] = v.z; wv2[4*m+3] = v.w;
        }
    }
    const float b2v = b2[j2];
    const float w3v = W3[j2];
    const float b3v = b3[0];

    // ---- stage features (coalesced read -> passthrough write + LDS) + xyz
    {
        const float4* fsrc = (const float4*)feats + (size_t)blockIdx.x * 1024;
        float4* fdst = (float4*)(out + OUT_FEAT_OFF) + (size_t)blockIdx.x * 1024;
#pragma unroll
        for (int i = 0; i < 4; ++i) {
            const int e = i * 256 + t;
            const float4 v = fsrc[e];
            fdst[e] = v;
            *(float4*)&sX[(e >> 4) * 68 + (e & 15) * 4] = v;
        }
        if (t < 192) {  // xyz into cols 64..66
            const float v = pts[(size_t)blockIdx.x * 192 + t];
            sX[(t / 3) * 68 + 64 + (t % 3)] = v;
        }
    }
    __syncthreads();

    // ---- layer 1: lane = j, 16 points; x via wave-uniform broadcast reads
#pragma unroll 4
    for (int p = 0; p < 16; ++p) {
        const float* xr = &sX[(prow + p) * 68];
        float4 xq[17];
#pragma unroll
        for (int c = 0; c < 17; ++c) xq[c] = *(const float4*)&xr[4 * c];
        float a0 = b1v, a1 = 0.f, a2 = 0.f, a3 = 0.f;
#pragma unroll
        for (int c = 0; c < 16; ++c) {
            a0 = fmaf(xq[c].x, wv1[4 * c + 0], a0);
            a1 = fmaf(xq[c].y, wv1[4 * c + 1], a1);
            a2 = fmaf(xq[c].z, wv1[4 * c + 2], a2);
            a3 = fmaf(xq[c].w, wv1[4 * c + 3], a3);
        }
        a0 = fmaf(xq[16].x, wv1[64], a0);   // xyz tail
        a1 = fmaf(xq[16].y, wv1[65], a1);
        a2 = fmaf(xq[16].z, wv1[66], a2);
        const float h = fmaxf((a0 + a1) + (a2 + a3), 0.f);
        sH1[(prow + p) * 68 + ln] = h;      // stride-1 b32: 2-way, free
    }
    // same wave wrote & reads its own rows: lgkmcnt ordering only, no barrier

    // ---- layer 2 + 3: lane = (j2, khalf); h1 via broadcast reads
    float zkeep = 0.f;
#pragma unroll 4
    for (int p = 0; p < 16; ++p) {
        const float* hr = &sH1[(prow + p) * 68 + (kh << 5)];
        float a0 = 0.f, a1 = 0.f;
#pragma unroll
        for (int m = 0; m < 8; ++m) {
            const float4 v = *(const float4*)&hr[4 * m];
            a0 = fmaf(v.x, wv2[4*m+0], a0);
            a1 = fmaf(v.y, wv2[4*m+1], a1);
            a0 = fmaf(v.z, wv2[4*m+2], a0);
            a1 = fmaf(v.w, wv2[4*m+3], a1);
        }
        float hs = a0 + a1;
        hs += __shfl_xor(hs, 32, 64);            // combine k-halves
        float t3 = fmaxf(hs + b2v, 0.f) * w3v;   // ReLU + W3 weight
        t3 += __shfl_xor(t3, 16, 64);            // reduce 32 j2-lanes
        t3 += __shfl_xor(t3, 8, 64);
        t3 += __shfl_xor(t3, 4, 64);
        t3 += __shfl_xor(t3, 2, 64);
        t3 += __shfl_xor(t3, 1, 64);
        if (ln == p) zkeep = t3 + b3v;           // point p's logit -> lane p
    }

    // ---- sigmoid + mask + coalesced 16-lane store
    if (ln < 16) {
        const int pp = blockIdx.x * 64 + prow + ln;
        float sc = 1.0f / (1.0f + expf(-zkeep));
        if (mask[pp] == 0) sc = 0.0f;
        out[pp] = sc;
    }

    // ---- arrival: last of 128 blocks of this batch does the stats
    const int batch = blockIdx.x >> 7;
    __syncthreads();  // drains stores (vmcnt(0) before s_barrier)
    if (t == 0) {
        const int old = __hip_atomic_fetch_add(&counters[batch], 1,
                                               __ATOMIC_ACQ_REL,
                                               __HIP_MEMORY_SCOPE_AGENT);
        sflag = (old == 127);
    }
    __syncthreads();
    if (!sflag) return;
    __builtin_amdgcn_fence(__ATOMIC_ACQUIRE, "agent");  // device-scope acquire

    // ================= stats for `batch` (256 threads, 32 pts/thread) ======
    float* scores = out + (size_t)batch * NPTS;
    const float* P = pts + (size_t)batch * NPTS * 3;
    const int* M = mask + (size_t)batch * NPTS;
    float* g = wsf + (size_t)batch * 40960;   // compacted xyz (global)

    // load 32 contiguous scores + build mask bitfield (order-preserving)
    float s[32];
    unsigned int mbits = 0;
#pragma unroll
    for (int i = 0; i < 8; ++i) {
        const float4 s4 = ((const float4*)scores)[t * 8 + i];
        s[4*i+0] = s4.x; s[4*i+1] = s4.y; s[4*i+2] = s4.z; s[4*i+3] = s4.w;
        const int4 m4 = ((const int4*)M)[t * 8 + i];
        mbits |= (m4.x != 0 ? 1u : 0u) << (4*i+0);
        mbits |= (m4.y != 0 ? 1u : 0u) << (4*i+1);
        mbits |= (m4.z != 0 ? 1u : 0u) << (4*i+2);
        mbits |= (m4.w != 0 ? 1u : 0u) << (4*i+3);
    }

    float ss = 0.f;
#pragma unroll
    for (int i = 0; i < 32; ++i) ss += s[i];  // scores already masked
    const float nleaf = blockReduceSum256((float)__popc(mbits));
    const float ssum = blockReduceSum256(ss);

    if (nleaf < 10.0f) {
        const float4 z4 = {0.f, 0.f, 0.f, 0.f};
#pragma unroll
        for (int i = 0; i < 8; ++i) ((float4*)scores)[t * 8 + i] = z4;
        if (t == 0) out[OUT_CONF_OFF + batch] = 0.0f;
        return;
    }

    // clarity
    const float mean = ssum / fmaxf(nleaf, 1.0f);
    float vs = 0.f;
#pragma unroll
    for (int i = 0; i < 32; ++i) {
        if (mbits & (1u << i)) {
            const float d0 = s[i] - mean;
            vs += d0 * d0;
        }
    }
    const float clarity = blockReduceSum256(vs) / fmaxf(nleaf - 1.0f, 1.0f);

    // order-preserving compaction of score > 0.7 points.
    // Wave-level inclusive shfl scan + 4 wave totals: 2 barriers.
    int c0 = 0;
#pragma unroll
    for (int i = 0; i < 32; ++i) c0 += (s[i] > 0.7f);
    int incl = c0;
#pragma unroll
    for (int o = 1; o < 64; o <<= 1) {
        const int u = __shfl_up(incl, o, 64);
        if (ln >= o) incl += u;
    }
    const int wv = t >> 6;
    if (ln == 63) swt[wv] = incl;
    __syncthreads();
    int woff = 0, cnt = 0;
#pragma unroll
    for (int i = 0; i < 4; ++i) {
        const int wt = swt[i];
        if (i < wv) woff += wt;
        cnt += wt;
    }
    int pos = woff + (incl - c0);  // exclusive prefix over thread order
#pragma unroll
    for (int i = 0; i < 32; ++i) {
        if (s[i] > 0.7f) {
            const int idx = t * 32 + i;
            g[3 * pos + 0] = P[3 * idx + 0];
            g[3 * pos + 1] = P[3 * idx + 1];
            g[3 * pos + 2] = P[3 * idx + 2];
            ++pos;
        }
    }
    __syncthreads();  // g visible; sX/sH1 dead -> smem becomes ddl

    // consecutive distances among first cnt selected points (dd in LDS;
    // npair <= 8191 < 8704)
    float* const ddl = smem;
    const int npair = cnt - 1;
    float dsum = 0.f;
#pragma unroll 4
    for (int i = t; i < npair; i += 256) {
        const float ax = g[3 * i + 0] - g[3 * i + 3];
        const float ay = g[3 * i + 1] - g[3 * i + 4];
        const float az = g[3 * i + 2] - g[3 * i + 5];
        const float d0 = sqrtf(ax * ax + ay * ay + az * az);
        ddl[i] = d0;
        dsum += d0;
    }
    const float dtot = blockReduceSum256(dsum);
    const float npf = (float)npair;
    const float dmean = dtot / fmaxf(npf, 1.0f);
    float dv = 0.f;
#pragma unroll 4
    for (int i = t; i < npair; i += 256) {
        const float e = ddl[i] - dmean;
        dv += e * e;
    }
    const float dvar = blockReduceSum256(dv) / fmaxf(npf - 1.0f, 1.0f);

    float cont = fminf(fmaxf(1.0f / (dvar + 1e-8f), 0.0f), 1.0f);
    if (!(cnt > 5)) cont = 0.0f;
    const float conf = fminf(fmaxf(clarity * cont, 0.0f), 1.0f);
    if (t == 0) out[OUT_CONF_OFF + batch] = conf;
}

// ---------------------------------------------------------------------------
extern "C" void kernel_launch(void* const* d_in, const int* in_sizes, int n_in,
                              void* d_out, int out_size, void* d_ws, size_t ws_size,
                              hipStream_t stream) {
    const float* points   = (const float*)d_in[0];
    const float* features = (const float*)d_in[1];
    const int*   leafmask = (const int*)d_in[2];
    const float* W1 = (const float*)d_in[3];
    const float* b1 = (const float*)d_in[4];
    const float* W2 = (const float*)d_in[5];
    const float* b2 = (const float*)d_in[6];
    const float* W3 = (const float*)d_in[7];
    const float* b3 = (const float*)d_in[8];
    float* out = (float*)d_out;
    int* counters = (int*)d_ws;
    float* wsf = (float*)d_ws + 64;  // stats scratch after counters

    (void)hipMemsetAsync(d_ws, 0, 64, stream);  // zero the 4 arrival counters
    fused_kernel<<<512, 256, 0, stream>>>(
        points, features, leafmask, W1, b1, W2, b2, W3, b3, out, counters, wsf);
}

// Round 4
// 108.020 us; speedup vs baseline: 1.4023x; 1.4023x over previous
//
#include <hip/hip_runtime.h>
#include <math.h>

// Shapes: B=4, N=8192, F=64; MLP: 67 -> 64 -> 32 -> 1
// d_out: [0,32768) boundary_prob | [32768,+2097152) features | last 4: conf
#define NB 4
#define NPTS 8192
#define OUT_FEAT_OFF 32768
#define OUT_CONF_OFF (32768 + 2097152)

// v_readlane: broadcast lane l's value to all lanes (SGPR result, pure VALU)
__device__ __forceinline__ float rlf(float v, int l) {
    return __int_as_float(__builtin_amdgcn_readlane(__float_as_int(v), l));
}

// ---------------------------------------------------------------------------
// block reduce over 256 threads
// ---------------------------------------------------------------------------
__device__ __forceinline__ float blockReduceSum256(float v) {
    __shared__ float sred[4];
#pragma unroll
    for (int o = 32; o > 0; o >>= 1) v += __shfl_down(v, o, 64);
    const int w = threadIdx.x >> 6, l = threadIdx.x & 63;
    __syncthreads();
    if (l == 0) sred[w] = v;
    __syncthreads();
    return sred[0] + sred[1] + sred[2] + sred[3];
}

// ---------------------------------------------------------------------------
// Fused kernel: 512 blocks x 256 threads (2 blocks/CU, 2 waves/SIMD).
// Block = 64 points; wave w owns points [16w,16w+16).
// MLP structure (counted register plan, ~85 VGPR -> no spill possible):
//  - X broadcast via v_readlane (VALU, deterministic): lane (kg=ln>>4,
//    p=ln&15) holds xk[i] = x[prow+p][4i+kg] (17 regs). Each of the wave's
//    16x68 x-values is readlane-broadcast exactly once (1088 VALU ops),
//    replacing round-0's ~270 DS-b128/thread (DS-pipe bound ~16us).
//  - L1 weights stream 4-at-a-time from LDS sW1T (2-way banks = free):
//    only 4 transient weight regs. Lane = L1 neuron j; h[16] accumulators.
//  - h parked in the dead sX region (same-wave rows, no barrier); L2 reads
//    it as 2-address b128 (2-way = free) against per-lane wv2[32]
//    (lane=(j2,kh), aligned global loads issued at kernel start).
//  - L3: xor-shuffle tree; logits parked lane==p; 16-lane coalesced store.
// Last-arriving block per batch computes the stats (tail verbatim from
// rounds 2/3, passed twice).
// ---------------------------------------------------------------------------
__global__ __launch_bounds__(256, 2) void fused_kernel(
    const float* __restrict__ pts,    // (B,N,3)
    const float* __restrict__ feats,  // (B,N,64)
    const int* __restrict__ mask,     // (B,N)
    const float* __restrict__ W1,     // (64,67)
    const float* __restrict__ b1,
    const float* __restrict__ W2,     // (32,64)
    const float* __restrict__ b2,
    const float* __restrict__ W3,     // (1,32)
    const float* __restrict__ b3,
    float* __restrict__ out,
    int* __restrict__ counters,       // 4 ints in ws, pre-zeroed
    float* __restrict__ wsf)          // stats scratch (after counters)
{
    // smem pool, aliased across phases:
    //   MLP : sX   = [0,4352)    64 rows x pitch 68 (feats, xyz, col67=0)
    //                            -> after L1, same region holds h1 (64x68)
    //         sW1T = [4352,8704) 68 rows x 64 (sW1T[k*64+j]=W1[j][k]; row67=0)
    //   stats: ddl = smem[0..8191)
    __shared__ float smem[8704];
    float* const sX = smem;
    float* const sW1T = smem + 4352;
    __shared__ int sflag;
    __shared__ int swt[4];

    const int t = threadIdx.x;
    const int ln = t & 63;
    const int w = __builtin_amdgcn_readfirstlane(t >> 6);  // wave id (SGPR)
    const int prow = w << 4;                               // wave's 16 rows

    // ---- L2 weights per lane (issued first; latency hides under staging)
    const int j2 = ln & 31, kh = ln >> 5;
    float wv2[32];
    {
        const float* w2r = W2 + j2 * 64 + (kh << 5);  // 16B aligned
#pragma unroll
        for (int m = 0; m < 8; ++m) {
            const float4 v = *(const float4*)&w2r[4 * m];
            wv2[4*m+0] = v.x; wv2[4*m+1] = v.y;
            wv2[4*m+2] = v.z; wv2[4*m+3] = v.w;
        }
    }
    const float b1v = b1[ln];     // lane = L1 neuron j
    const float b2v = b2[j2];
    const float w3v = W3[j2];
    const float b3v = b3[0];

    // ---- stage: feats (coalesced -> passthrough + sX), xyz, W1 transposed
    {
        const float4* fsrc = (const float4*)feats + (size_t)blockIdx.x * 1024;
        float4* fdst = (float4*)(out + OUT_FEAT_OFF) + (size_t)blockIdx.x * 1024;
#pragma unroll
        for (int i = 0; i < 4; ++i) {
            const int e = i * 256 + t;
            const float4 v = fsrc[e];
            fdst[e] = v;
            *(float4*)&sX[(e >> 4) * 68 + (e & 15) * 4] = v;
        }
        if (t < 192) {  // xyz into cols 64..66
            const float v = pts[(size_t)blockIdx.x * 192 + t];
            sX[(t / 3) * 68 + 64 + (t % 3)] = v;
        }
        if (t < 64) sX[t * 68 + 67] = 0.0f;        // pad col (k=67)
        for (int idx = t; idx < 4288; idx += 256)   // 67x64 transpose
            sW1T[idx] = W1[(idx & 63) * 67 + (idx >> 6)];
        if (t < 64) sW1T[67 * 64 + t] = 0.0f;       // pad row (k=67)
    }
    __syncthreads();

    // ---- xk: lane (kg,p) holds x[prow+p][4i+kg], i=0..16 (2-way banks)
    const int kg = ln >> 4, pl = ln & 15;
    float xk[17];
#pragma unroll
    for (int i = 0; i < 17; ++i)
        xk[i] = sX[(prow + pl) * 68 + 4 * i + kg];

    // ---- layer 1: lane = j; k ascending, single accumulator per point
    float h[16];
#pragma unroll
    for (int p = 0; p < 16; ++p) h[p] = b1v;
#pragma unroll
    for (int c = 0; c < 17; ++c) {   // k-chunk [4c,4c+4)
        const float wk0 = sW1T[(4 * c + 0) * 64 + ln];
        const float wk1 = sW1T[(4 * c + 1) * 64 + ln];
        const float wk2 = sW1T[(4 * c + 2) * 64 + ln];
        const float wk3 = sW1T[(4 * c + 3) * 64 + ln];
#pragma unroll
        for (int p = 0; p < 16; ++p) {
            h[p] = fmaf(rlf(xk[c],  0 + p), wk0, h[p]);  // k=4c+0 (kg=0)
            h[p] = fmaf(rlf(xk[c], 16 + p), wk1, h[p]);  // k=4c+1 (kg=1)
            h[p] = fmaf(rlf(xk[c], 32 + p), wk2, h[p]);  // k=4c+2 (kg=2)
            h[p] = fmaf(rlf(xk[c], 48 + p), wk3, h[p]);  // k=4c+3 (kg=3)
        }
    }
#pragma unroll
    for (int p = 0; p < 16; ++p) h[p] = fmaxf(h[p], 0.0f);

    // ---- park h1 in the (dead) sX region: row prow+p, col ln.
    //      Same-wave rows only -> no barrier; compiler orders via lgkmcnt.
#pragma unroll
    for (int p = 0; p < 16; ++p)
        sX[(prow + p) * 68 + ln] = h[p];

    // ---- layer 2 + 3: lane = (j2,kh); h via 2-address b128 (2-way, free)
    float zkeep = 0.0f;
#pragma unroll
    for (int p = 0; p < 16; ++p) {
        const float* hr = &sX[(prow + p) * 68 + (kh << 5)];
        float a0 = 0.f, a1 = 0.f;
#pragma unroll
        for (int m = 0; m < 8; ++m) {
            const float4 v = *(const float4*)&hr[4 * m];
            a0 = fmaf(v.x, wv2[4*m+0], a0);
            a1 = fmaf(v.y, wv2[4*m+1], a1);
            a0 = fmaf(v.z, wv2[4*m+2], a0);
            a1 = fmaf(v.w, wv2[4*m+3], a1);
        }
        float hs = a0 + a1;
        hs += __shfl_xor(hs, 32, 64);            // combine k-halves
        float t3 = fmaxf(hs + b2v, 0.f) * w3v;   // ReLU + W3 weight
        t3 += __shfl_xor(t3, 16, 64);            // reduce 32 j2-lanes
        t3 += __shfl_xor(t3, 8, 64);
        t3 += __shfl_xor(t3, 4, 64);
        t3 += __shfl_xor(t3, 2, 64);
        t3 += __shfl_xor(t3, 1, 64);
        if (ln == p) zkeep = t3 + b3v;           // point p's logit -> lane p
    }

    // ---- sigmoid + mask + coalesced 16-lane store
    if (ln < 16) {
        const int pp = blockIdx.x * 64 + prow + ln;
        float sc = 1.0f / (1.0f + expf(-zkeep));
        if (mask[pp] == 0) sc = 0.0f;
        out[pp] = sc;
    }

    // ---- arrival: last of 128 blocks of this batch does the stats
    const int batch = blockIdx.x >> 7;
    __syncthreads();  // drains stores (vmcnt(0) before s_barrier)
    if (t == 0) {
        const int old = __hip_atomic_fetch_add(&counters[batch], 1,
                                               __ATOMIC_ACQ_REL,
                                               __HIP_MEMORY_SCOPE_AGENT);
        sflag = (old == 127);
    }
    __syncthreads();
    if (!sflag) return;
    __builtin_amdgcn_fence(__ATOMIC_ACQUIRE, "agent");  // device-scope acquire

    // ================= stats for `batch` (256 threads, 32 pts/thread) ======
    float* scores = out + (size_t)batch * NPTS;
    const float* P = pts + (size_t)batch * NPTS * 3;
    const int* M = mask + (size_t)batch * NPTS;
    float* g = wsf + (size_t)batch * 40960;   // compacted xyz (global)

    // load 32 contiguous scores + build mask bitfield (order-preserving)
    float s[32];
    unsigned int mbits = 0;
#pragma unroll
    for (int i = 0; i < 8; ++i) {
        const float4 s4 = ((const float4*)scores)[t * 8 + i];
        s[4*i+0] = s4.x; s[4*i+1] = s4.y; s[4*i+2] = s4.z; s[4*i+3] = s4.w;
        const int4 m4 = ((const int4*)M)[t * 8 + i];
        mbits |= (m4.x != 0 ? 1u : 0u) << (4*i+0);
        mbits |= (m4.y != 0 ? 1u : 0u) << (4*i+1);
        mbits |= (m4.z != 0 ? 1u : 0u) << (4*i+2);
        mbits |= (m4.w != 0 ? 1u : 0u) << (4*i+3);
    }

    float ss = 0.f;
#pragma unroll
    for (int i = 0; i < 32; ++i) ss += s[i];  // scores already masked
    const float nleaf = blockReduceSum256((float)__popc(mbits));
    const float ssum = blockReduceSum256(ss);

    if (nleaf < 10.0f) {
        const float4 z4 = {0.f, 0.f, 0.f, 0.f};
#pragma unroll
        for (int i = 0; i < 8; ++i) ((float4*)scores)[t * 8 + i] = z4;
        if (t == 0) out[OUT_CONF_OFF + batch] = 0.0f;
        return;
    }

    // clarity
    const float mean = ssum / fmaxf(nleaf, 1.0f);
    float vs = 0.f;
#pragma unroll
    for (int i = 0; i < 32; ++i) {
        if (mbits & (1u << i)) {
            const float d0 = s[i] - mean;
            vs += d0 * d0;
        }
    }
    const float clarity = blockReduceSum256(vs) / fmaxf(nleaf - 1.0f, 1.0f);

    // order-preserving compaction of score > 0.7 points.
    // Wave-level inclusive shfl scan + 4 wave totals: 2 barriers.
    int c0 = 0;
#pragma unroll
    for (int i = 0; i < 32; ++i) c0 += (s[i] > 0.7f);
    int incl = c0;
#pragma unroll
    for (int o = 1; o < 64; o <<= 1) {
        const int u = __shfl_up(incl, o, 64);
        if (ln >= o) incl += u;
    }
    const int wv = t >> 6;
    if (ln == 63) swt[wv] = incl;
    __syncthreads();
    int woff = 0, cnt = 0;
#pragma unroll
    for (int i = 0; i < 4; ++i) {
        const int wt = swt[i];
        if (i < wv) woff += wt;
        cnt += wt;
    }
    int pos = woff + (incl - c0);  // exclusive prefix over thread order
#pragma unroll
    for (int i = 0; i < 32; ++i) {
        if (s[i] > 0.7f) {
            const int idx = t * 32 + i;
            g[3 * pos + 0] = P[3 * idx + 0];
            g[3 * pos + 1] = P[3 * idx + 1];
            g[3 * pos + 2] = P[3 * idx + 2];
            ++pos;
        }
    }
    __syncthreads();  // g visible; MLP smem dead -> becomes ddl

    // consecutive distances among first cnt selected points (dd in LDS;
    // npair <= 8191 < 8704)
    float* const ddl = smem;
    const int npair = cnt - 1;
    float dsum = 0.f;
#pragma unroll 4
    for (int i = t; i < npair; i += 256) {
        const float ax = g[3 * i + 0] - g[3 * i + 3];
        const float ay = g[3 * i + 1] - g[3 * i + 4];
        const float az = g[3 * i + 2] - g[3 * i + 5];
        const float d0 = sqrtf(ax * ax + ay * ay + az * az);
        ddl[i] = d0;
        dsum += d0;
    }
    const float dtot = blockReduceSum256(dsum);
    const float npf = (float)npair;
    const float dmean = dtot / fmaxf(npf, 1.0f);
    float dv = 0.f;
#pragma unroll 4
    for (int i = t; i < npair; i += 256) {
        const float e = ddl[i] - dmean;
        dv += e * e;
    }
    const float dvar = blockReduceSum256(dv) / fmaxf(npf - 1.0f, 1.0f);

    float cont = fminf(fmaxf(1.0f / (dvar + 1e-8f), 0.0f), 1.0f);
    if (!(cnt > 5)) cont = 0.0f;
    const float conf = fminf(fmaxf(clarity * cont, 0.0f), 1.0f);
    if (t == 0) out[OUT_CONF_OFF + batch] = conf;
}

// ---------------------------------------------------------------------------
extern "C" void kernel_launch(void* const* d_in, const int* in_sizes, int n_in,
                              void* d_out, int out_size, void* d_ws, size_t ws_size,
                              hipStream_t stream) {
    const float* points   = (const float*)d_in[0];
    const float* features = (const float*)d_in[1];
    const int*   leafmask = (const int*)d_in[2];
    const float* W1 = (const float*)d_in[3];
    const float* b1 = (const float*)d_in[4];
    const float* W2 = (const float*)d_in[5];
    const float* b2 = (const float*)d_in[6];
    const float* W3 = (const float*)d_in[7];
    const float* b3 = (const float*)d_in[8];
    float* out = (float*)d_out;
    int* counters = (int*)d_ws;
    float* wsf = (float*)d_ws + 64;  // stats scratch after counters

    (void)hipMemsetAsync(d_ws, 0, 64, stream);  // zero the 4 arrival counters
    fused_kernel<<<512, 256, 0, stream>>>(
        points, features, leafmask, W1, b1, W2, b2, W3, b3, out, counters, wsf);
}